// Round 13
// baseline (364.740 us; speedup 1.0000x reference)
//
#include <hip/hip_runtime.h>
#include <hip/hip_bf16.h>

// HypergraphGNN on MI355X (gfx950).
// B=4 P=8 N=E=2000 IN=16 HID=128 NL=3 MULT=4. All f32 inputs; internal bf16 MFMA.
//
// Round-13: N-FOLD. For fixed b, the 8 p-panels of xTb/eTb ([bp][128][2048])
// are contiguous -> each heavy GEMM is really M=2048, N=1024, K=2048 per b.
// Tile 128x256 (2 p's), 4 waves of 64x128, BK=32, at round-6's proven
// occupancy (2 blocks/CU) and schedule (static 2-buffer dbuf, counted
// vmcnt(6), setprio MFMA cluster, chunk^((row>>1)&3) swizzle). Per-barrier
// MFMA doubles (128 vs 64); ds_read and staging bytes per MFMA drop 25%.
// Stage-2 fuses per-wave by p (each wave's 128-col half is one p x same W).
// x0_k: dropped the dead xb write (MLP reads xb written by the last layer).
// Lessons kept: frag reads via LDS only (R7); no M-fat tiles (R11/R12); no
// cross-K wave-splitting (R10).

typedef __attribute__((ext_vector_type(8))) short bf16x8;
typedef __attribute__((ext_vector_type(4))) float f32x4;

#define GLL16(gp, lp) __builtin_amdgcn_global_load_lds(                      \
    (const __attribute__((address_space(1))) void*)(gp),                     \
    (__attribute__((address_space(3))) void*)(lp), 16, 0, 0)

__device__ __forceinline__ unsigned short f2bf(float v) {
  __hip_bfloat16 h = __float2bfloat16(v);
  return __builtin_bit_cast(unsigned short, h);
}
__device__ __forceinline__ float bf2f(unsigned short u) {
  unsigned int x = ((unsigned int)u) << 16;
  return __builtin_bit_cast(float, x);
}

// ---------------------------------------------------------------------------
// H f32 -> Hb (straight) + HTb (transposed), bf16, padded 2000->2048 w/ zeros
__global__ void convH_k(const float* __restrict__ H,
                        unsigned short* __restrict__ Hb,
                        unsigned short* __restrict__ HTb) {
  int b  = blockIdx.z;
  int n0 = blockIdx.y * 32, e0 = blockIdx.x * 32;
  __shared__ float t[32][33];
  int tx = threadIdx.x & 31, ty = threadIdx.x >> 5;
  for (int r = ty; r < 32; r += 8) {
    int n = n0 + r, e = e0 + tx;
    float v = (n < 2000 && e < 2000) ? H[((long)b * 2000 + n) * 2000 + e] : 0.f;
    t[r][tx] = v;
    Hb[((long)b * 2048 + n) * 2048 + e] = f2bf(v);
  }
  __syncthreads();
  for (int r = ty; r < 32; r += 8) {
    HTb[((long)b * 2048 + (e0 + r)) * 2048 + (n0 + tx)] = f2bf(t[tx][r]);
  }
}

// generic f32 [R][C] -> bf16 [C][R]
__global__ void transposeW_k(const float* __restrict__ src,
                             unsigned short* __restrict__ dst, int R, int C) {
  __shared__ float t[32][33];
  int c0 = blockIdx.x * 32, r0 = blockIdx.y * 32;
  int tx = threadIdx.x & 31, ty = threadIdx.x >> 5;
  for (int rr = ty; rr < 32; rr += 8) {
    int rI = r0 + rr, cI = c0 + tx;
    t[rr][tx] = (rI < R && cI < C) ? src[(long)rI * C + cI] : 0.f;
  }
  __syncthreads();
  for (int rr = ty; rr < 32; rr += 8) {
    int cO = c0 + rr, rO = r0 + tx;
    if (cO < C && rO < R) dst[(long)cO * R + rO] = f2bf(t[tx][rr]);
  }
}

// x0 = nf @ W_in (K=16) -> xTb only (xb from x0 was dead: MLP reads the xb
// written by the last layer). Thread owns one d-column, 64 nodes contiguous.
__global__ __launch_bounds__(256) void x0_k(
    const float* __restrict__ nf, const float* __restrict__ Win,
    unsigned short* __restrict__ xTb) {
  __shared__ float nfs[128][16];
  __shared__ float wins[2048];

  int bp = blockIdx.y;
  int n0 = blockIdx.x * 128;
  int tid = threadIdx.x;

  {
    int r = tid >> 1, c = (tid & 1) * 8;
    int n = n0 + r;
    float4 v0 = make_float4(0.f, 0.f, 0.f, 0.f), v1 = v0;
    if (n < 2000) {
      const float* src = nf + ((long)bp * 2000 + n) * 16 + c;
      v0 = *(const float4*)src;
      v1 = *(const float4*)(src + 4);
    }
    *(float4*)&nfs[r][c]     = v0;
    *(float4*)&nfs[r][c + 4] = v1;
  }
  {
    int base = tid * 8;
    float4 a = *(const float4*)(Win + base);
    float4 b = *(const float4*)(Win + base + 4);
    *(float4*)&wins[base]     = a;
    *(float4*)&wins[base + 4] = b;
  }
  __syncthreads();

  int d = tid & 127, half = tid >> 7;
  float wcol[16];
#pragma unroll
  for (int k = 0; k < 16; k++) wcol[k] = wins[k * 128 + d];

  unsigned short* dst = xTb + ((long)bp * 128 + d) * 2048 + n0 + half * 64;
#pragma unroll
  for (int oct = 0; oct < 8; oct++) {
    bf16x8 pk;
#pragma unroll
    for (int j = 0; j < 8; j++) {
      int nl = half * 64 + oct * 8 + j;
      float v = 0.f;
#pragma unroll
      for (int k = 0; k < 16; k++) v += nfs[nl][k] * wcol[k];
      pk[j] = (short)f2bf(v);
    }
    *(bf16x8*)(dst + oct * 8) = pk;  // 16B contiguous, sector-complete
  }
}

// wf = W2 @ Wdec  (512x128 @ 128 -> 512)
__global__ void wfuse_k(const float* __restrict__ W2, const float* __restrict__ Wdec,
                        float* __restrict__ wf) {
  int i = blockIdx.x * 256 + threadIdx.x;
  if (i < 512) {
    float s = 0.f;
#pragma unroll 8
    for (int j = 0; j < 128; j++) s += W2[i * 128 + j] * Wdec[j];
    wf[i] = s;
  }
}

// ---------------------------------------------------------------------------
// Fused heavy GEMM, N-folded: per b, acc = A[2048][2048] @ BT[1024][2048]^T.
// Tile 128x256 (rows m0..+128, cols = 2 p-panels), 4 waves of 64x128.
// Stage-2: out = relu(acc_p @ W) per p (wave's col-half = one p), Wt global.
// Writes Ct (transposed, per p) and optionally Cn (normal, per p).
// Grid 256 (16 mblk x 4 ntl x 4 b), XCD-swizzled, 256 threads.
template <int WN, int WT>
__global__ __launch_bounds__(256, 2) void gemm_fused(
    const unsigned short* __restrict__ A, int lda, long strideA,
    const unsigned short* __restrict__ BT, long strideBT,
    const unsigned short* __restrict__ Wt,
    unsigned short* __restrict__ Cn, int ldc, long strideCn,
    unsigned short* __restrict__ Ct, int ldct, long strideCt, int K) {
  // XCD decode: XCD c owns orig [c*32,+32) = all 16 mblk x 2 rest values
  int wgid = blockIdx.x;
  int orig = (wgid & 7) * 32 + (wgid >> 3);
  int mblk = orig & 15;
  int rest = orig >> 4;       // 0..15
  int ntl  = rest & 3;        // n-tile (pair of p's)
  int b    = rest >> 2;       // batch
  int m0   = mblk * 128;
  int bp0  = b * 8 + ntl * 2;
  A += (long)b * strideA;
  const unsigned short* BTb = BT + (long)bp0 * strideBT;  // [256][2048] contig

  // 64 KB LDS arena: dbuf = 2 x 12288 shorts ([A 4096 | B 8192]) in [0,24576);
  // Gs 128x256 bf16 (32768 shorts) / GsT 2x[128][128] alias the full arena.
  __shared__ unsigned short smem[32768];

  int tid  = threadIdx.x;
  int lane = tid & 63;
  int w    = tid >> 6;
  int wr   = w >> 1, wc = w & 1;  // wave: rows [wr*64,+64), cols [wc*128,+128)
  int fr   = lane & 15;           // frag row (A) / col (B,C)
  int fg   = lane >> 4;           // k-chunk (inputs) / row-subgroup (C/D)

  // staging (BK=32): A 512 chunks (2/thr), B 1024 chunks (4/thr), 16B each.
  // LDS dest linear; global chunk = slot ^ ((row>>1)&3)  [<=2-way, free].
  const unsigned short* Agp[2];
  const unsigned short* Bgp[4];
#pragma unroll
  for (int i = 0; i < 2; i++) {
    int s = i * 256 + tid, row = s >> 2, gc = (s & 3) ^ ((row >> 1) & 3);
    Agp[i] = A + (long)(m0 + row) * lda + gc * 8;
  }
#pragma unroll
  for (int i = 0; i < 4; i++) {
    int s = i * 256 + tid, row = s >> 2, gc = (s & 3) ^ ((row >> 1) & 3);
    Bgp[i] = BTb + (long)row * 2048 + gc * 8;
  }

#define STAGE(sel, tk) do {                                                  \
    int _k = (tk) * 32;                                                      \
    _Pragma("unroll")                                                        \
    for (int i = 0; i < 2; i++)                                              \
      GLL16(Agp[i] + _k, smem + (sel) * 12288 + (i * 256 + tid) * 8);        \
    _Pragma("unroll")                                                        \
    for (int i = 0; i < 4; i++)                                              \
      GLL16(Bgp[i] + _k, smem + (sel) * 12288 + 4096 + (i * 256 + tid) * 8); \
  } while (0)

  f32x4 acc[4][8] = {};
  const int cIdx = (fg ^ ((fr >> 1) & 3)) * 8;  // lane-constant frag swizzle

#define COMPUTE(sel) do {                                                    \
    const unsigned short* As_ = smem + (sel) * 12288;                        \
    const unsigned short* Bs_ = As_ + 4096;                                  \
    bf16x8 af[4], bv[8];                                                     \
    _Pragma("unroll")                                                        \
    for (int m = 0; m < 4; m++)                                              \
      af[m] = *(const bf16x8*)&As_[(wr * 64 + m * 16 + fr) * 32 + cIdx];     \
    _Pragma("unroll")                                                        \
    for (int n = 0; n < 8; n++)                                              \
      bv[n] = *(const bf16x8*)&Bs_[(wc * 128 + n * 16 + fr) * 32 + cIdx];    \
    __builtin_amdgcn_s_setprio(1);                                           \
    _Pragma("unroll")                                                        \
    for (int m = 0; m < 4; m++)                                              \
      _Pragma("unroll")                                                      \
      for (int n = 0; n < 8; n++)                                            \
        acc[m][n] = __builtin_amdgcn_mfma_f32_16x16x32_bf16(af[m], bv[n],    \
                                                            acc[m][n], 0, 0, 0); \
    __builtin_amdgcn_s_setprio(0);                                           \
  } while (0)

#define VMW(n) asm volatile("s_waitcnt vmcnt(" #n ")" ::: "memory")
#define BARR __builtin_amdgcn_s_barrier()
#define SCH0 __builtin_amdgcn_sched_barrier(0)

  int nt = K >> 5;  // 64 K-tiles of 32 (even)

  STAGE(0, 0);
  int t = 0;
  for (; t + 2 < nt; t += 2) {
    STAGE(1, t + 1);
    VMW(6); BARR; SCH0;   // tile t landed; t+1 in flight
    COMPUTE(0);
    BARR;                 // buf0 free
    STAGE(0, t + 2);
    VMW(6); BARR; SCH0;   // tile t+1 landed; t+2 in flight
    COMPUTE(1);
    BARR;                 // buf1 free
  }
  STAGE(1, nt - 1);
  VMW(6); BARR; SCH0;
  COMPUTE(0);
  BARR;
  VMW(0); BARR; SCH0;
  COMPUTE(1);
#undef STAGE
#undef COMPUTE
  __syncthreads();  // all dbuf reads done before Gs aliases the arena

  // ---- stage-1 acc -> Gs bf16 row-major [128][256], chunk^(row&7) swizzle --
  unsigned short* Gs = smem;
#pragma unroll
  for (int m = 0; m < 4; m++) {
#pragma unroll
    for (int n = 0; n < 8; n++) {
      int rowb = wr * 64 + m * 16 + fg * 4;
      int col  = wc * 128 + n * 16 + fr;
      int ch = col >> 3, ci = col & 7;
#pragma unroll
      for (int r = 0; r < 4; r++) {
        int row = rowb + r;
        Gs[row * 256 + ((ch ^ (row & 7)) * 8) + ci] = f2bf(acc[m][n][r]);
      }
    }
  }
  __syncthreads();

  // ---- stage 2: per wave, out = relu(G_p @ W); p = wc. A=Gs cols of p,
  // B=Wt global (L2-hot). K=128 in 4 chunks of 32.
  f32x4 acc2[4][8] = {};
#pragma unroll
  for (int kk = 0; kk < 4; kk++) {
    bf16x8 a2[4], b2[8];
#pragma unroll
    for (int m = 0; m < 4; m++) {
      int row = wr * 64 + m * 16 + fr;
      int ch = wc * 16 + kk * 4 + fg;
      a2[m] = *(const bf16x8*)&Gs[row * 256 + ((ch ^ (row & 7)) * 8)];
    }
#pragma unroll
    for (int n = 0; n < 8; n++) {
      int row = n * 16 + fr;  // d_out
      b2[n] = *(const bf16x8*)&Wt[row * 128 + (kk * 4 + fg) * 8];
    }
#pragma unroll
    for (int m = 0; m < 4; m++)
#pragma unroll
      for (int n = 0; n < 8; n++)
        acc2[m][n] = __builtin_amdgcn_mfma_f32_16x16x32_bf16(a2[m], b2[n], acc2[m][n], 0, 0, 0);
  }

  // optional normal-layout write (last dispatch only), per-p
  if (WN) {
#pragma unroll
    for (int m = 0; m < 4; m++) {
#pragma unroll
      for (int n = 0; n < 8; n++) {
        int rowb = m0 + wr * 64 + m * 16 + fg * 4;
        int col  = n * 16 + fr;  // d
        unsigned short* p = Cn + (bp0 + wc) * strideCn + (long)rowb * ldc + col;
        p[0]       = f2bf(fmaxf(acc2[m][n][0], 0.f));
        p[ldc]     = f2bf(fmaxf(acc2[m][n][1], 0.f));
        p[2 * ldc] = f2bf(fmaxf(acc2[m][n][2], 0.f));
        p[3 * ldc] = f2bf(fmaxf(acc2[m][n][3], 0.f));
      }
    }
  }

  if (WT) {
    // relu'd acc2 -> GsT[p][col d 0..127][row 0..127] bf16 (slot^col&7),
    // then coalesced 16B stores: Ct row = d, 256B span per (p,d).
    __syncthreads();  // all Gs reads done before overwrite
    unsigned short* GsT = smem;  // 2 x 16384 shorts
#pragma unroll
    for (int m = 0; m < 4; m++) {
#pragma unroll
      for (int n = 0; n < 8; n++) {
        int rowb = wr * 64 + m * 16 + fg * 4;  // rowb&7 in {0,4}
        int col  = n * 16 + fr;                // d
        int slot = (rowb >> 3) ^ (col & 7);
        ushort4 pk;
        pk.x = f2bf(fmaxf(acc2[m][n][0], 0.f));
        pk.y = f2bf(fmaxf(acc2[m][n][1], 0.f));
        pk.z = f2bf(fmaxf(acc2[m][n][2], 0.f));
        pk.w = f2bf(fmaxf(acc2[m][n][3], 0.f));
        *(ushort4*)&GsT[wc * 16384 + col * 128 + slot * 8 + (rowb & 7)] = pk;
      }
    }
    __syncthreads();
#pragma unroll
    for (int i = 0; i < 16; i++) {
      int s = i * 256 + tid;            // 4096 chunks: p(1) x col(7) x slot(4)
      int pI = s >> 11, col = (s >> 4) & 127, slot = s & 15;
      int l = slot ^ (col & 7);         // logical row-chunk
      bf16x8 v = *(const bf16x8*)&GsT[pI * 16384 + col * 128 + slot * 8];
      *(bf16x8*)(Ct + (bp0 + pI) * strideCt + (long)col * ldct + m0 + l * 8) = v;
    }
  }
}

// ---------------------------------------------------------------------------
// Fused MLP: out[row] = 10*tanh( (sum_i relu(x@W1)[row][i]*wf[i]) / sqrt(128) )
__global__ __launch_bounds__(256) void mlp_k(
    const unsigned short* __restrict__ X,    // [65536][128] bf16 (padded rows)
    const unsigned short* __restrict__ W1T,  // [512][128] bf16
    const float* __restrict__ wf,            // [512]
    float* __restrict__ out) {
  __shared__ unsigned short Xs[128 * 128];
  __shared__ unsigned short Bs[128 * 128];
  __shared__ float rowacc[128];

  int tid  = threadIdx.x;
  int lane = tid & 63;
  int w    = tid >> 6, wr = w >> 1, wc = w & 1;
  int fr   = lane & 15, fg = lane >> 4;
  long m0  = (long)blockIdx.x * 128;

#pragma unroll
  for (int i = 0; i < 8; i++) {
    int s = i * 256 + tid;
    int r = s >> 4, c = (s & 15) ^ (r & 7);
    GLL16(X + (m0 + r) * 128 + c * 8, (unsigned short*)Xs + s * 8);
  }
  if (tid < 128) rowacc[tid] = 0.f;

  float rs[4][4] = {};

  for (int nb = 0; nb < 4; nb++) {
#pragma unroll
    for (int i = 0; i < 8; i++) {
      int s = i * 256 + tid;
      int r = s >> 4, c = (s & 15) ^ (r & 7);
      GLL16(W1T + (long)(nb * 128 + r) * 128 + c * 8, (unsigned short*)Bs + s * 8);
    }
    __syncthreads();

    f32x4 acc[4][4] = {};
#pragma unroll
    for (int kk = 0; kk < 4; kk++) {
      bf16x8 a2[4], b2[4];
#pragma unroll
      for (int m = 0; m < 4; m++) {
        int row = wr * 64 + m * 16 + fr;
        int c = kk * 4 + fg;
        a2[m] = *(const bf16x8*)&Xs[row * 128 + ((c ^ (row & 7)) * 8)];
      }
#pragma unroll
      for (int n = 0; n < 4; n++) {
        int row = wc * 64 + n * 16 + fr;
        int c = kk * 4 + fg;
        b2[n] = *(const bf16x8*)&Bs[row * 128 + ((c ^ (row & 7)) * 8)];
      }
#pragma unroll
      for (int m = 0; m < 4; m++)
#pragma unroll
        for (int n = 0; n < 4; n++)
          acc[m][n] = __builtin_amdgcn_mfma_f32_16x16x32_bf16(a2[m], b2[n], acc[m][n], 0, 0, 0);
    }

#pragma unroll
    for (int n = 0; n < 4; n++) {
      float wv = wf[nb * 128 + wc * 64 + n * 16 + fr];
#pragma unroll
      for (int m = 0; m < 4; m++)
#pragma unroll
        for (int r = 0; r < 4; r++)
          rs[m][r] += fmaxf(acc[m][n][r], 0.f) * wv;
    }
    __syncthreads();
  }

#pragma unroll
  for (int m = 0; m < 4; m++)
#pragma unroll
    for (int r = 0; r < 4; r++) {
      float v = rs[m][r];
      v += __shfl_xor(v, 1, 64);
      v += __shfl_xor(v, 2, 64);
      v += __shfl_xor(v, 4, 64);
      v += __shfl_xor(v, 8, 64);
      if (fr == 0) atomicAdd(&rowacc[wr * 64 + m * 16 + fg * 4 + r], v);
    }
  __syncthreads();

  if (tid < 128) {
    long row = m0 + tid;
    int bp = (int)(row >> 11), n = (int)(row & 2047);
    if (n < 2000)
      out[(long)bp * 2000 + n] = 10.f * tanhf(rowacc[tid] * 0.08838834764831843f);
  }
}

// ---------------------------------------------------------------------------
extern "C" void kernel_launch(void* const* d_in, const int* in_sizes, int n_in,
                              void* d_out, int out_size, void* d_ws, size_t ws_size,
                              hipStream_t stream) {
  const float* nf    = (const float*)d_in[0];
  const float* H     = (const float*)d_in[1];
  const float* Win   = (const float*)d_in[2];
  const float* edgeW = (const float*)d_in[3];
  const float* nodeW = (const float*)d_in[4];
  const float* W1    = (const float*)d_in[5];
  const float* W2    = (const float*)d_in[6];
  const float* Wdec  = (const float*)d_in[7];
  float* out = (float*)d_out;

  char* ws = (char*)d_ws;
  unsigned short* Hb   = (unsigned short*)(ws + 0);          // 33.55 MB
  unsigned short* HTb  = (unsigned short*)(ws + 33554432);   // 33.55 MB
  unsigned short* xb   = (unsigned short*)(ws + 67108864);   // 16.78 MB
  unsigned short* xTb  = (unsigned short*)(ws + 83886080);   // 16.78 MB
  unsigned short* eTb  = (unsigned short*)(ws + 100663296);  // 16.78 MB
  unsigned short* edgeWT = (unsigned short*)(ws + 117440512);
  unsigned short* nodeWT = (unsigned short*)(ws + 117538816);
  unsigned short* W1T    = (unsigned short*)(ws + 117637120);
  float*          wf     = (float*)(ws + 117768192);
  (void)ws_size; (void)in_sizes; (void)n_in; (void)out_size;

  // ---- input prep ----
  convH_k<<<dim3(64, 64, 4), 256, 0, stream>>>(H, Hb, HTb);
  for (int l = 0; l < 3; l++) {
    transposeW_k<<<dim3(4, 4), 256, 0, stream>>>(edgeW + l * 16384, edgeWT + l * 16384, 128, 128);
    transposeW_k<<<dim3(4, 4), 256, 0, stream>>>(nodeW + l * 16384, nodeWT + l * 16384, 128, 128);
  }
  transposeW_k<<<dim3(16, 4), 256, 0, stream>>>(W1, W1T, 128, 512);
  wfuse_k<<<2, 256, 0, stream>>>(W2, Wdec, wf);
  x0_k<<<dim3(16, 32), 256, 0, stream>>>(nf, Win, xTb);

  // ---- 3 hypergraph layers, 2 fused dispatches each (N-folded per b) ----
  for (int l = 0; l < 3; l++) {
    // L1: e = relu((H^T @ x) @ We) -> eT
    gemm_fused<0, 1><<<dim3(256), 256, 0, stream>>>(
        HTb, 2048, 2048L * 2048, xTb, 128L * 2048,
        edgeWT + l * 16384,
        nullptr, 0, 0, eTb, 2048, 128L * 2048, 2048);
    // L2: x = relu((H @ e) @ Wn) -> xT (+ xb on last layer for MLP)
    if (l < 2) {
      gemm_fused<0, 1><<<dim3(256), 256, 0, stream>>>(
          Hb, 2048, 2048L * 2048, eTb, 128L * 2048,
          nodeWT + l * 16384,
          nullptr, 0, 0, xTb, 2048, 128L * 2048, 2048);
    } else {
      gemm_fused<1, 1><<<dim3(256), 256, 0, stream>>>(
          Hb, 2048, 2048L * 2048, eTb, 128L * 2048,
          nodeWT + l * 16384,
          xb, 128, 2048L * 128, xTb, 2048, 128L * 2048, 2048);
    }
  }

  // ---- fused MLP + decode ----
  mlp_k<<<dim3(512), 256, 0, stream>>>(xb, W1T, wf, out);
}